// Round 1
// baseline (180.148 us; speedup 1.0000x reference)
//
#include <hip/hip_runtime.h>

// LTCN layer: NB=64 blocks x K=64 neurons, BATCH=4096, all blocks independent.
// One WG = (block j, 64 batch rows): 4x 64x64x64 bf16 MFMA GEMMs + tanh + update.
// j==0: fwd GEMM is u_t(256) @ W_in^T, done as 4 staged K-chunks of 64.

#define IN_DIM 256
#define K 64
#define NB 64
#define BATCH 4096
#define NTOT (NB * K)          // 4096
#define DTC 0.05f
#define TAU_EPS 1e-6f
#define LDSTR 72               // padded LDS row stride (bf16 elems), 16B-aligned rows

typedef __bf16 bf16;
typedef bf16 bf16x8 __attribute__((ext_vector_type(8)));
typedef bf16 bf16x4 __attribute__((ext_vector_type(4)));
typedef float f32x4 __attribute__((ext_vector_type(4)));

__device__ __forceinline__ float fast_tanh(float x) {
    // tanh(x) = 1 - 2/(e^{2x}+1); saturates correctly for |x| large.
    float e = __expf(2.0f * x);
    return 1.0f - 2.0f * __builtin_amdgcn_rcpf(e + 1.0f);
}

// Stage a 64x64 f32 tile (global row stride gstride) into bf16 LDS (stride LDSTR).
// 256 threads x 4 iters x float4: coalesced 256B-per-16-lane rows.
__device__ __forceinline__ void stage64(bf16* __restrict__ dst,
                                        const float* __restrict__ src,
                                        int gstride, int tid) {
#pragma unroll
    for (int it = 0; it < 4; ++it) {
        int idx = it * 256 + tid;
        int r = idx >> 4;
        int c4 = idx & 15;
        float4 v = *(const float4*)(src + r * gstride + (c4 << 2));
        bf16x4 p = { (bf16)v.x, (bf16)v.y, (bf16)v.z, (bf16)v.w };
        *(bf16x4*)(dst + r * LDSTR + (c4 << 2)) = p;  // 8B aligned
    }
}

__global__ __launch_bounds__(256)
void ltcn_kernel(const float* __restrict__ y, const float* __restrict__ u_t,
                 const float* __restrict__ tau_raw,
                 const float* __restrict__ W_in_w, const float* __restrict__ W_in_b,
                 const float* __restrict__ W_fwd_w, const float* __restrict__ W_fwd_b,
                 const float* __restrict__ W_rec_w, const float* __restrict__ W_rec_b,
                 const float* __restrict__ E_l, const float* __restrict__ E_l_r,
                 float* __restrict__ out) {
    __shared__ bf16 sY  [64 * LDSTR];  // y_cur tile (A operand, rec GEMM)
    __shared__ bf16 sP  [64 * LDSTR];  // y_prev / u_t chunk; reused as net_rec
    __shared__ bf16 sWf [64 * LDSTR];  // W_fwd / W_in chunk; reused as net_out
    __shared__ bf16 sWr [64 * LDSTR];
    __shared__ bf16 sEl [64 * LDSTR];
    __shared__ bf16 sElr[64 * LDSTR];
    __shared__ float sInvTau[64], sBf[64], sBr[64];

    const int tid  = threadIdx.x;
    const int j    = blockIdx.y;          // block index 0..63
    const int b0   = blockIdx.x * 64;     // batch tile base
    const int wave = tid >> 6;
    const int lane = tid & 63;
    const int quad = lane >> 4;
    const int l16  = lane & 15;

    // ---- Phase 0: stage rec-side tensors ----
    stage64(sY,   y       + (size_t)b0 * NTOT + j * K, NTOT, tid);
    stage64(sWr,  W_rec_w + (size_t)j * K * K,          K,   tid);
    stage64(sEl,  E_l     + (size_t)j * K * K,          K,   tid);
    stage64(sElr, E_l_r   + (size_t)j * K * K,          K,   tid);
    if (tid < 64) {
        float x = tau_raw[j * K + tid];
        float sp = (x > 15.0f) ? x : log1pf(__expf(x));
        sInvTau[tid] = 1.0f / (sp + TAU_EPS);
        sBf[tid] = (j == 0) ? W_in_b[tid] : W_fwd_b[(j - 1) * K + tid];
        sBr[tid] = W_rec_b[j * K + tid];
    }

    const int aoff = (wave * 16 + l16) * LDSTR + quad * 8;  // A-frag base offset

    // ---- fwd / input GEMM: accF[ct] = (prev|u_t) @ W^T, 4 col-tiles per wave ----
    f32x4 accF[4] = {};
    const int rounds = (j == 0) ? 4 : 1;
    for (int kc = 0; kc < rounds; ++kc) {
        if (j == 0) {
            stage64(sP,  u_t    + (size_t)b0 * IN_DIM + kc * 64, IN_DIM, tid);
            stage64(sWf, W_in_w + kc * 64,                        IN_DIM, tid);
        } else {
            stage64(sP,  y       + (size_t)b0 * NTOT + (j - 1) * K, NTOT, tid);
            stage64(sWf, W_fwd_w + (size_t)(j - 1) * K * K,          K,   tid);
        }
        __syncthreads();
#pragma unroll
        for (int k0 = 0; k0 < 64; k0 += 32) {
            bf16x8 a = *(const bf16x8*)(sP + aoff + k0);
#pragma unroll
            for (int ct = 0; ct < 4; ++ct) {
                bf16x8 b = *(const bf16x8*)(sWf + (ct * 16 + l16) * LDSTR + quad * 8 + k0);
                accF[ct] = __builtin_amdgcn_mfma_f32_16x16x32_bf16(a, b, accF[ct], 0, 0, 0);
            }
        }
        __syncthreads();  // safe to restage / overwrite sP,sWf after this
    }

    // ---- rec GEMM: accR[ct] = y_cur @ W_rec^T ----
    f32x4 accR[4] = {};
#pragma unroll
    for (int k0 = 0; k0 < 64; k0 += 32) {
        bf16x8 a = *(const bf16x8*)(sY + aoff + k0);
#pragma unroll
        for (int ct = 0; ct < 4; ++ct) {
            bf16x8 b = *(const bf16x8*)(sWr + (ct * 16 + l16) * LDSTR + quad * 8 + k0);
            accR[ct] = __builtin_amdgcn_mfma_f32_16x16x32_bf16(a, b, accR[ct], 0, 0, 0);
        }
    }

    // ---- tanh + write nets (C-layout -> LDS, reuse sWf=net_out, sP=net_rec) ----
#pragma unroll
    for (int ct = 0; ct < 4; ++ct) {
#pragma unroll
        for (int r = 0; r < 4; ++r) {
            int m = wave * 16 + quad * 4 + r;
            int n = ct * 16 + l16;
            float no = fast_tanh(accF[ct][r] + sBf[n]);
            float nr = fast_tanh(accR[ct][r] + sBr[n]);
            sWf[m * LDSTR + n] = (bf16)no;
            sP [m * LDSTR + n] = (bf16)nr;
        }
    }
    __syncthreads();

    // ---- drive GEMM: accD = net_out @ E_l^T + net_rec @ E_l_r^T ----
    f32x4 accD[4] = {};
#pragma unroll
    for (int k0 = 0; k0 < 64; k0 += 32) {
        bf16x8 aO = *(const bf16x8*)(sWf + aoff + k0);
        bf16x8 aR = *(const bf16x8*)(sP  + aoff + k0);
#pragma unroll
        for (int ct = 0; ct < 4; ++ct) {
            bf16x8 bO = *(const bf16x8*)(sEl  + (ct * 16 + l16) * LDSTR + quad * 8 + k0);
            accD[ct] = __builtin_amdgcn_mfma_f32_16x16x32_bf16(aO, bO, accD[ct], 0, 0, 0);
            bf16x8 bR = *(const bf16x8*)(sElr + (ct * 16 + l16) * LDSTR + quad * 8 + k0);
            accD[ct] = __builtin_amdgcn_mfma_f32_16x16x32_bf16(aR, bR, accD[ct], 0, 0, 0);
        }
    }

    // ---- epilogue: y_new = (y + dt*drive) / (1 + dt*decay), f32 y from global (L2-hot) ----
#pragma unroll
    for (int ct = 0; ct < 4; ++ct) {
#pragma unroll
        for (int r = 0; r < 4; ++r) {
            int m = wave * 16 + quad * 4 + r;
            int n = ct * 16 + l16;
            size_t gi = (size_t)(b0 + m) * NTOT + j * K + n;
            float yv = y[gi];
            float no = (float)sWf[m * LDSTR + n];
            float nr = (float)sP [m * LDSTR + n];
            float decay = sInvTau[n] + fabsf(no) + fabsf(nr);
            float drive = accD[ct][r];
            out[gi] = (yv + DTC * drive) * __builtin_amdgcn_rcpf(1.0f + DTC * decay);
        }
    }
}

extern "C" void kernel_launch(void* const* d_in, const int* in_sizes, int n_in,
                              void* d_out, int out_size, void* d_ws, size_t ws_size,
                              hipStream_t stream) {
    const float* y       = (const float*)d_in[0];
    const float* u_t     = (const float*)d_in[1];
    const float* tau_raw = (const float*)d_in[2];
    const float* W_in_w  = (const float*)d_in[3];
    const float* W_in_b  = (const float*)d_in[4];
    const float* W_fwd_w = (const float*)d_in[5];
    const float* W_fwd_b = (const float*)d_in[6];
    const float* W_rec_w = (const float*)d_in[7];
    const float* W_rec_b = (const float*)d_in[8];
    const float* E_l     = (const float*)d_in[9];
    const float* E_l_r   = (const float*)d_in[10];
    float* out = (float*)d_out;

    dim3 grid(BATCH / 64, NB);
    hipLaunchKernelGGL(ltcn_kernel, grid, dim3(256), 0, stream,
                       y, u_t, tau_raw, W_in_w, W_in_b, W_fwd_w, W_fwd_b,
                       W_rec_w, W_rec_b, E_l, E_l_r, out);
}

// Round 2
// 163.351 us; speedup vs baseline: 1.1028x; 1.1028x over previous
//
#include <hip/hip_runtime.h>

// LTCN layer: NB=64 blocks x K=64 neurons, BATCH=4096, blocks independent.
// One WG = (block j, 64 batch rows). R2: A-operands (y_cur/y_prev/u_t) loaded
// global->register (no LDS), weights in 4 LDS buffers (37KB -> 4 WG/CU),
// nets round-trip through the dead weight buffers, decay terms stay in regs.

#define IN_DIM 256
#define K 64
#define NB 64
#define BATCH 4096
#define NTOT (NB * K)          // 4096
#define DTC 0.05f
#define TAU_EPS 1e-6f
#define LDSTR 72               // padded LDS row stride (bf16), 16B-aligned rows

typedef __bf16 bf16;
typedef bf16 bf16x8 __attribute__((ext_vector_type(8)));
typedef bf16 bf16x4 __attribute__((ext_vector_type(4)));
typedef float f32x4 __attribute__((ext_vector_type(4)));

__device__ __forceinline__ float fast_tanh(float x) {
    float e = __expf(2.0f * x);
    return 1.0f - 2.0f * __builtin_amdgcn_rcpf(e + 1.0f);
}

// Stage a 64x64 f32 tile (row stride gstride) into bf16 LDS (stride LDSTR).
__device__ __forceinline__ void stage64(bf16* __restrict__ dst,
                                        const float* __restrict__ src,
                                        int gstride, int tid) {
#pragma unroll
    for (int it = 0; it < 4; ++it) {
        int idx = it * 256 + tid;
        int r = idx >> 4;
        int c4 = idx & 15;
        float4 v = *(const float4*)(src + r * gstride + (c4 << 2));
        bf16x4 p = { (bf16)v.x, (bf16)v.y, (bf16)v.z, (bf16)v.w };
        *(bf16x4*)(dst + r * LDSTR + (c4 << 2)) = p;
    }
}

// Load one 64-wide A-operand row slice straight into two bf16x8 fragments.
// rowp points at (row, col0 + quad*8); frags cover k = 0..31 and 32..63.
__device__ __forceinline__ void load_afrag(const float* __restrict__ rowp,
                                           bf16x8& f0, bf16x8& f1) {
    float4 a0 = *(const float4*)(rowp);
    float4 a1 = *(const float4*)(rowp + 4);
    float4 a2 = *(const float4*)(rowp + 32);
    float4 a3 = *(const float4*)(rowp + 36);
    f0 = (bf16x8){ (bf16)a0.x, (bf16)a0.y, (bf16)a0.z, (bf16)a0.w,
                   (bf16)a1.x, (bf16)a1.y, (bf16)a1.z, (bf16)a1.w };
    f1 = (bf16x8){ (bf16)a2.x, (bf16)a2.y, (bf16)a2.z, (bf16)a2.w,
                   (bf16)a3.x, (bf16)a3.y, (bf16)a3.z, (bf16)a3.w };
}

__global__ __launch_bounds__(256, 4)
void ltcn_kernel(const float* __restrict__ y, const float* __restrict__ u_t,
                 const float* __restrict__ tau_raw,
                 const float* __restrict__ W_in_w, const float* __restrict__ W_in_b,
                 const float* __restrict__ W_fwd_w, const float* __restrict__ W_fwd_b,
                 const float* __restrict__ W_rec_w, const float* __restrict__ W_rec_b,
                 const float* __restrict__ E_l, const float* __restrict__ E_l_r,
                 float* __restrict__ out) {
    __shared__ bf16 sWf [64 * LDSTR];  // W_fwd / W_in chunk; reused as net_out
    __shared__ bf16 sWr [64 * LDSTR];  // W_rec;             reused as net_rec
    __shared__ bf16 sEl [64 * LDSTR];
    __shared__ bf16 sElr[64 * LDSTR];
    __shared__ float sInvTau[64], sBf[64], sBr[64];

    const int tid  = threadIdx.x;
    const int j    = blockIdx.y;
    const int b0   = blockIdx.x * 64;
    const int wave = tid >> 6;
    const int lane = tid & 63;
    const int quad = lane >> 4;
    const int l16  = lane & 15;
    const int am   = wave * 16 + l16;      // A-fragment row within batch tile

    // ---- Phase 1: issue everything independent up front ----
    stage64(sWr,  W_rec_w + (size_t)j * K * K, K, tid);
    stage64(sEl,  E_l     + (size_t)j * K * K, K, tid);
    stage64(sElr, E_l_r   + (size_t)j * K * K, K, tid);

    bf16x8 yc0, yc1;                       // y_cur A fragments (rec GEMM)
    load_afrag(y + (size_t)(b0 + am) * NTOT + j * K + quad * 8, yc0, yc1);

    bf16x8 yp0, yp1;                       // y_prev or u_t chunk fragments
    if (j != 0) {
        stage64(sWf, W_fwd_w + (size_t)(j - 1) * K * K, K, tid);
        load_afrag(y + (size_t)(b0 + am) * NTOT + (j - 1) * K + quad * 8, yp0, yp1);
    } else {
        stage64(sWf, W_in_w, IN_DIM, tid); // W_in cols 0..63
        load_afrag(u_t + (size_t)(b0 + am) * IN_DIM + quad * 8, yp0, yp1);
    }
    if (tid < 64) {
        float x = tau_raw[j * K + tid];
        float sp = (x > 15.0f) ? x : log1pf(__expf(x));
        sInvTau[tid] = 1.0f / (sp + TAU_EPS);
        sBf[tid] = (j == 0) ? W_in_b[tid] : W_fwd_b[(j - 1) * K + tid];
        sBr[tid] = W_rec_b[j * K + tid];
    }
    __syncthreads();

    // ---- Phase 2: fwd + rec GEMMs ----
    f32x4 accF[4] = {}, accR[4] = {};
    const int boff = quad * 8;
    if (j != 0) {
#pragma unroll
        for (int ct = 0; ct < 4; ++ct) {
            const bf16* br = sWr + (ct * 16 + l16) * LDSTR + boff;
            const bf16* bw = sWf + (ct * 16 + l16) * LDSTR + boff;
            accR[ct] = __builtin_amdgcn_mfma_f32_16x16x32_bf16(yc0, *(const bf16x8*)br,        accR[ct], 0, 0, 0);
            accR[ct] = __builtin_amdgcn_mfma_f32_16x16x32_bf16(yc1, *(const bf16x8*)(br + 32), accR[ct], 0, 0, 0);
            accF[ct] = __builtin_amdgcn_mfma_f32_16x16x32_bf16(yp0, *(const bf16x8*)bw,        accF[ct], 0, 0, 0);
            accF[ct] = __builtin_amdgcn_mfma_f32_16x16x32_bf16(yp1, *(const bf16x8*)(bw + 32), accF[ct], 0, 0, 0);
        }
    } else {
#pragma unroll
        for (int ct = 0; ct < 4; ++ct) {
            const bf16* br = sWr + (ct * 16 + l16) * LDSTR + boff;
            accR[ct] = __builtin_amdgcn_mfma_f32_16x16x32_bf16(yc0, *(const bf16x8*)br,        accR[ct], 0, 0, 0);
            accR[ct] = __builtin_amdgcn_mfma_f32_16x16x32_bf16(yc1, *(const bf16x8*)(br + 32), accR[ct], 0, 0, 0);
        }
        for (int kc = 0; kc < 4; ++kc) {
#pragma unroll
            for (int ct = 0; ct < 4; ++ct) {
                const bf16* bw = sWf + (ct * 16 + l16) * LDSTR + boff;
                accF[ct] = __builtin_amdgcn_mfma_f32_16x16x32_bf16(yp0, *(const bf16x8*)bw,        accF[ct], 0, 0, 0);
                accF[ct] = __builtin_amdgcn_mfma_f32_16x16x32_bf16(yp1, *(const bf16x8*)(bw + 32), accF[ct], 0, 0, 0);
            }
            if (kc < 3) {
                load_afrag(u_t + (size_t)(b0 + am) * IN_DIM + (kc + 1) * 64 + quad * 8, yp0, yp1);
                __syncthreads();
                stage64(sWf, W_in_w + (kc + 1) * 64, IN_DIM, tid);
                __syncthreads();
            }
        }
    }

    // ---- Phase 3: tanh (in regs), decay terms stay resident ----
    float absum[4][4];
#pragma unroll
    for (int ct = 0; ct < 4; ++ct) {
        float bfv = sBf[ct * 16 + l16];
        float brv = sBr[ct * 16 + l16];
#pragma unroll
        for (int r = 0; r < 4; ++r) {
            float no = fast_tanh(accF[ct][r] + bfv);
            float nr = fast_tanh(accR[ct][r] + brv);
            accF[ct][r] = no;
            accR[ct][r] = nr;
            absum[ct][r] = fabsf(no) + fabsf(nr);
        }
    }
    __syncthreads();  // all B-reads of sWf/sWr finished before overwrite

    // nets: C-layout -> LDS (reuse sWf = net_out, sWr = net_rec)
#pragma unroll
    for (int ct = 0; ct < 4; ++ct) {
#pragma unroll
        for (int r = 0; r < 4; ++r) {
            int m = wave * 16 + quad * 4 + r;
            int n = ct * 16 + l16;
            sWf[m * LDSTR + n] = (bf16)accF[ct][r];
            sWr[m * LDSTR + n] = (bf16)accR[ct][r];
        }
    }
    __syncthreads();

    // ---- Phase 4: drive GEMM + epilogue ----
    float ye[4][4];  // y at C-layout positions (L2-hot re-read, issued early)
    const float* yep = y + (size_t)(b0 + wave * 16 + quad * 4) * NTOT + (size_t)j * K + l16;
#pragma unroll
    for (int ct = 0; ct < 4; ++ct)
#pragma unroll
        for (int r = 0; r < 4; ++r)
            ye[ct][r] = yep[(size_t)r * NTOT + ct * 16];

    const bf16* aOp = sWf + am * LDSTR + quad * 8;
    const bf16* aRp = sWr + am * LDSTR + quad * 8;
    bf16x8 aO0 = *(const bf16x8*)aOp,        aO1 = *(const bf16x8*)(aOp + 32);
    bf16x8 aR0 = *(const bf16x8*)aRp,        aR1 = *(const bf16x8*)(aRp + 32);

    f32x4 accD[4] = {};
#pragma unroll
    for (int ct = 0; ct < 4; ++ct) {
        const bf16* bo = sEl  + (ct * 16 + l16) * LDSTR + quad * 8;
        const bf16* br = sElr + (ct * 16 + l16) * LDSTR + quad * 8;
        accD[ct] = __builtin_amdgcn_mfma_f32_16x16x32_bf16(aO0, *(const bf16x8*)bo,        accD[ct], 0, 0, 0);
        accD[ct] = __builtin_amdgcn_mfma_f32_16x16x32_bf16(aO1, *(const bf16x8*)(bo + 32), accD[ct], 0, 0, 0);
        accD[ct] = __builtin_amdgcn_mfma_f32_16x16x32_bf16(aR0, *(const bf16x8*)br,        accD[ct], 0, 0, 0);
        accD[ct] = __builtin_amdgcn_mfma_f32_16x16x32_bf16(aR1, *(const bf16x8*)(br + 32), accD[ct], 0, 0, 0);
    }

    float it4[4];
#pragma unroll
    for (int ct = 0; ct < 4; ++ct) it4[ct] = sInvTau[ct * 16 + l16];

#pragma unroll
    for (int ct = 0; ct < 4; ++ct) {
#pragma unroll
        for (int r = 0; r < 4; ++r) {
            size_t gi = (size_t)(b0 + wave * 16 + quad * 4 + r) * NTOT + j * K + ct * 16 + l16;
            float decay = it4[ct] + absum[ct][r];
            out[gi] = (ye[ct][r] + DTC * accD[ct][r]) * __builtin_amdgcn_rcpf(1.0f + DTC * decay);
        }
    }
}

extern "C" void kernel_launch(void* const* d_in, const int* in_sizes, int n_in,
                              void* d_out, int out_size, void* d_ws, size_t ws_size,
                              hipStream_t stream) {
    const float* y       = (const float*)d_in[0];
    const float* u_t     = (const float*)d_in[1];
    const float* tau_raw = (const float*)d_in[2];
    const float* W_in_w  = (const float*)d_in[3];
    const float* W_in_b  = (const float*)d_in[4];
    const float* W_fwd_w = (const float*)d_in[5];
    const float* W_fwd_b = (const float*)d_in[6];
    const float* W_rec_w = (const float*)d_in[7];
    const float* W_rec_b = (const float*)d_in[8];
    const float* E_l     = (const float*)d_in[9];
    const float* E_l_r   = (const float*)d_in[10];
    float* out = (float*)d_out;

    dim3 grid(BATCH / 64, NB);
    hipLaunchKernelGGL(ltcn_kernel, grid, dim3(256), 0, stream,
                       y, u_t, tau_raw, W_in_w, W_in_b, W_fwd_w, W_fwd_b,
                       W_rec_w, W_rec_b, E_l, E_l_r, out);
}